// Round 14
// baseline (47.177 us; speedup 1.0000x reference)
//
#include <hip/hip_runtime.h>
#include <math.h>

#define NC     1000
#define NBLK   2000     // 2 column-half blocks per class
#define DIM    2048
#define HALF   1024
#define NBATCH 8192
#define MAXN   1024     // sidx capacity (2 KB); n ~ Poisson(8.2), max ~25

typedef float f32x4 __attribute__((ext_vector_type(4)));
typedef int   i32x4 __attribute__((ext_vector_type(4)));

// R11 structure with: 2 KB sidx (was 16 KB) and loss merged into k_main via
// FIRE-AND-FORGET float atomicAdd (return unused -> no serialization; the
// R5/R6/R13 failures were all atomics whose RETURN was consumed).
// k_fin is a 1-thread pure-launch finisher.
__global__ __launch_bounds__(256) void k_main(
        const int*   __restrict__ y,
        const float* __restrict__ feat,
        const float* __restrict__ centers,
        float* __restrict__ grad_out,     // d_out + 1 (4B-aligned only)
        float* __restrict__ loss_acc) {   // zeroed each call
    const int c = blockIdx.x >> 1;
    const int h = blockIdx.x & 1;
    const int t = threadIdx.x;
    const int col = h * HALF + t * 4;

    const f32x4 cen = *(const f32x4*)(centers + (size_t)c * DIM + col);

    __shared__ unsigned short sidx[MAXN];
    __shared__ int scur;
    if (t == 0) scur = 0;
    __syncthreads();

    // vectorized scan of y: 8192 ints as 2048 int4, 8 per thread
    const i32x4* y4 = (const i32x4*)y;
    for (int j = t; j < NBATCH / 4; j += 256) {
        i32x4 v = y4[j];
        int base = 4 * j;
        if (v.x == c) sidx[atomicAdd(&scur, 1) & (MAXN - 1)] = (unsigned short)(base + 0);
        if (v.y == c) sidx[atomicAdd(&scur, 1) & (MAXN - 1)] = (unsigned short)(base + 1);
        if (v.z == c) sidx[atomicAdd(&scur, 1) & (MAXN - 1)] = (unsigned short)(base + 2);
        if (v.w == c) sidx[atomicAdd(&scur, 1) & (MAXN - 1)] = (unsigned short)(base + 3);
    }
    __syncthreads();
    const int n = scur;

    f32x4 acc = (f32x4)(0.f);
    float lsum = 0.f;

    int r = 0;
    for (; r + 4 <= n; r += 4) {
        int i0 = sidx[r], i1 = sidx[r+1], i2 = sidx[r+2], i3 = sidx[r+3];
        f32x4 v0 = *(const f32x4*)(feat + (size_t)i0 * DIM + col);
        f32x4 v1 = *(const f32x4*)(feat + (size_t)i1 * DIM + col);
        f32x4 v2 = *(const f32x4*)(feat + (size_t)i2 * DIM + col);
        f32x4 v3 = *(const f32x4*)(feat + (size_t)i3 * DIM + col);
        acc += v0 + v1 + v2 + v3;
        f32x4 d0 = v0 - cen, d1 = v1 - cen, d2 = v2 - cen, d3 = v3 - cen;
        f32x4 sq = d0 * d0 + d1 * d1 + d2 * d2 + d3 * d3;
        lsum += sq.x + sq.y + sq.z + sq.w;
    }
    for (; r < n; ++r) {
        int i0 = sidx[r];
        f32x4 v0 = *(const f32x4*)(feat + (size_t)i0 * DIM + col);
        acc += v0;
        f32x4 d0 = v0 - cen;
        f32x4 sq = d0 * d0;
        lsum += sq.x + sq.y + sq.z + sq.w;
    }

    // grad = coeff * (centers - mean); coeff = n/(1+n); zero when n == 0
    f32x4 g = (f32x4)(0.f);
    if (n > 0) {
        float fn = (float)n;
        float inv = 1.0f / fn;
        float coeff = fn / (1.0f + fn);
        g = coeff * (cen - acc * inv);
    }
    float* go = grad_out + (size_t)c * DIM + col;   // odd base -> scalar stores
    go[0] = g.x; go[1] = g.y; go[2] = g.z; go[3] = g.w;

    // block-reduce lsum (4 waves) -> ONE fire-and-forget atomic per block
    for (int sh = 32; sh > 0; sh >>= 1) lsum += __shfl_down(lsum, sh);
    __shared__ float red[4];
    if ((t & 63) == 0) red[t >> 6] = lsum;
    __syncthreads();
    if (t == 0) atomicAdd(loss_acc, red[0] + red[1] + red[2] + red[3]);
}

__global__ void k_fin(const float* __restrict__ loss_acc, float* __restrict__ out) {
    out[0] = 0.5f * sqrtf(loss_acc[0]) / (float)NBATCH;
}

extern "C" void kernel_launch(void* const* d_in, const int* in_sizes, int n_in,
                              void* d_out, int out_size, void* d_ws, size_t ws_size,
                              hipStream_t stream) {
    const int*   y       = (const int*)d_in[0];
    const float* feat    = (const float*)d_in[1];
    const float* centers = (const float*)d_in[2];
    float* out = (float*)d_out;
    float* loss_acc = (float*)d_ws;

    hipMemsetAsync(d_ws, 0, 4, stream);
    k_main<<<NBLK, 256, 0, stream>>>(y, feat, centers, out + 1, loss_acc);
    k_fin <<<1, 1, 0, stream>>>(loss_acc, out);
}